// Round 4
// baseline (788.353 us; speedup 1.0000x reference)
//
#include <hip/hip_runtime.h>

#define N_NODES 50000
#define E_EDGES 800000
#define NPW 8   // nodes per wave (consecutive; CSR ranges contiguous)

__device__ __forceinline__ float __rlf(float v, int l) {
    return __int_as_float(__builtin_amdgcn_readlane(__float_as_int(v), l));
}

// ============================ CSR build =====================================
__global__ __launch_bounds__(256) void k_hist(
    const int* __restrict__ ei, int* __restrict__ cnt)
{
    const int e = blockIdx.x * 256 + threadIdx.x;
    if (e < E_EDGES) atomicAdd(&cnt[ei[E_EDGES + e]], 1);
}

// single block, 1024 threads: exclusive prefix over cnt -> rowptr, cursor
__global__ __launch_bounds__(1024) void k_scan(
    const int* __restrict__ cnt, int* __restrict__ rowptr, int* __restrict__ cursor)
{
    __shared__ int part[1024];
    const int tid = threadIdx.x;
    const int CH = 49;                      // 1024*49 >= 50000
    const int base = tid * CH;
    int sum = 0;
    for (int c = 0; c < CH; ++c) {
        const int i = base + c;
        if (i < N_NODES) sum += cnt[i];
    }
    part[tid] = sum;
    __syncthreads();
    for (int off = 1; off < 1024; off <<= 1) {
        int v = part[tid];
        int u = (tid >= off) ? part[tid - off] : 0;
        __syncthreads();
        part[tid] = v + u;
        __syncthreads();
    }
    int run = (tid > 0) ? part[tid - 1] : 0;
    for (int c = 0; c < CH; ++c) {
        const int i = base + c;
        if (i < N_NODES) {
            rowptr[i] = run;
            cursor[i] = run;
            run += cnt[i];
        }
    }
    if (tid == 1023) rowptr[N_NODES] = part[1023];
}

__global__ __launch_bounds__(256) void k_scatter(
    const int* __restrict__ ei, int* __restrict__ cursor, int2* __restrict__ pairs)
{
    const int e = blockIdx.x * 256 + threadIdx.x;
    if (e < E_EDGES) {
        const int dst = ei[E_EDGES + e];
        const int pos = atomicAdd(&cursor[dst], 1);
        pairs[pos] = make_int2(ei[e], e);
    }
}

// ============ CSR-order edge-attr pre-scale (kills gather deps) =============
__global__ __launch_bounds__(256) void k_prep(
    const int2* __restrict__ pairs, const float* __restrict__ eattr,
    const float* __restrict__ ew, float* __restrict__ eaw, int* __restrict__ srcs)
{
    const int t = blockIdx.x * 256 + threadIdx.x;
    const int pos = t >> 2;
    if (pos >= E_EDGES) return;
    const int q = t & 3;
    const int2 p = pairs[pos];
    if (q == 0) srcs[pos] = p.x;
    const float w = ew[p.y];
    const float4 a = *((const float4*)(eattr + (size_t)p.y * 16) + q);
    *((float4*)(eaw + (size_t)pos * 16) + q) =
        make_float4(a.x * w, a.y * w, a.z * w, a.w * w);
}

// ================== Weight transposes (once, tiny) ==========================
// WT segments (float offsets): WT11@0 [64][128], WT12@8192 [128][128],
// WT21@24576, WT22@40960, WTo@57344 [128][128] (j>=100 zero-padded),
// WeT1@73728 [16][64], WeT2@74752 [16][128].
__global__ __launch_bounds__(256) void k_wt(
    const float* __restrict__ W11, const float* __restrict__ W12,
    const float* __restrict__ W21, const float* __restrict__ W22,
    const float* __restrict__ Wo,
    const float* __restrict__ We1, const float* __restrict__ We2,
    float* __restrict__ WT)
{
    const int bid = blockIdx.x;
    const int tid = threadIdx.x;
    if (bid < 288) {
        const float* src; int KIN, JOUT, lbase, obase;
        if (bid < 32)       { src = W11; KIN = 64;  JOUT = 128; lbase = 0;   obase = 0; }
        else if (bid < 96)  { src = W12; KIN = 128; JOUT = 128; lbase = 32;  obase = 8192; }
        else if (bid < 160) { src = W21; KIN = 128; JOUT = 128; lbase = 96;  obase = 24576; }
        else if (bid < 224) { src = W22; KIN = 128; JOUT = 128; lbase = 160; obase = 40960; }
        else                { src = Wo;  KIN = 128; JOUT = 100; lbase = 224; obase = 57344; }
        const int idx = (bid - lbase) * 256 + tid;   // < KIN*128
        const int k = idx >> 7, j = idx & 127;
        WT[obase + idx] = (j < JOUT) ? src[j * KIN + k] : 0.f;
    } else if (bid < 292) {                   // WeT1[k][d] = We1[d][k]
        const int idx = (bid - 288) * 256 + tid;     // < 1024
        const int k = idx >> 6, d = idx & 63;
        WT[73728 + idx] = We1[d * 16 + k];
    } else {                                  // WeT2[k][d] = We2[d][k]
        const int idx = (bid - 292) * 256 + tid;     // < 2048
        const int k = idx >> 7, d = idx & 127;
        WT[74752 + idx] = We2[d * 16 + k];
    }
}

// ===================== Edge layer 1 (CSR gather, 16->64) ====================
// Wave processes NPW consecutive nodes: weight/bias prologue (now COALESCED
// via WeT1) loaded once per 8 nodes instead of per node; rp reads are s_load
// (node wave-uniform). Inner loop: chunk-broadcast + chained FMA + prefetch.
__global__ __launch_bounds__(256, 4) void k_edge1(
    const int* __restrict__ rp, const int* __restrict__ srcs,
    const float* __restrict__ eaw,
    const float* __restrict__ WeT1, const float* __restrict__ be1,
    const float* __restrict__ x, float* __restrict__ out)
{
    const int lane = threadIdx.x & 63;
    const int wv = __builtin_amdgcn_readfirstlane(threadIdx.x >> 6);
    const int n0 = blockIdx.x * (4 * NPW) + wv * NPW;
    if (n0 >= N_NODES) return;

    float wr[16];
#pragma unroll
    for (int k = 0; k < 16; ++k) wr[k] = WeT1[k * 64 + lane];   // coalesced 256B
    const float bias = be1[lane];

    for (int ni = 0; ni < NPW; ++ni) {
        const int node = n0 + ni;
        if (node >= N_NODES) break;
        const int beg = rp[node], end = rp[node + 1];           // s_load
        float acc = 0.f;

        if (beg < end) {
            int l16 = beg + (lane & 15);
            int sl = srcs[l16 < end ? l16 : end - 1];
            float4 ev = *(const float4*)(eaw + (size_t)beg * 16 + lane * 4);
            for (int c = beg; c < end; c += 16) {
                const int cp = (c + 16 < end) ? c + 16 : c;     // prefetch chunk
                const int lp = cp + (lane & 15);
                const int sln = srcs[lp < end ? lp : end - 1];
                const float4 evn = *(const float4*)(eaw + (size_t)cp * 16 + lane * 4);
                const int n = end - c < 16 ? end - c : 16;      // uniform per wave
#pragma unroll 8
                for (int j = 0; j < n; ++j) {
                    const int src = __builtin_amdgcn_readlane(sl, j);
                    const float hv = x[(size_t)src * 64 + lane];
                    const int L = 4 * j;
                    float d = bias;
                    d = fmaf(__rlf(ev.x, L),     wr[0],  d);
                    d = fmaf(__rlf(ev.y, L),     wr[1],  d);
                    d = fmaf(__rlf(ev.z, L),     wr[2],  d);
                    d = fmaf(__rlf(ev.w, L),     wr[3],  d);
                    d = fmaf(__rlf(ev.x, L + 1), wr[4],  d);
                    d = fmaf(__rlf(ev.y, L + 1), wr[5],  d);
                    d = fmaf(__rlf(ev.z, L + 1), wr[6],  d);
                    d = fmaf(__rlf(ev.w, L + 1), wr[7],  d);
                    d = fmaf(__rlf(ev.x, L + 2), wr[8],  d);
                    d = fmaf(__rlf(ev.y, L + 2), wr[9],  d);
                    d = fmaf(__rlf(ev.z, L + 2), wr[10], d);
                    d = fmaf(__rlf(ev.w, L + 2), wr[11], d);
                    d = fmaf(__rlf(ev.x, L + 3), wr[12], d);
                    d = fmaf(__rlf(ev.y, L + 3), wr[13], d);
                    d = fmaf(__rlf(ev.z, L + 3), wr[14], d);
                    d = fmaf(__rlf(ev.w, L + 3), wr[15], d);
                    acc += fmaxf(hv + d, 0.f);
                }
                sl = sln; ev = evn;
            }
        }
        out[(size_t)node * 64 + lane] = x[(size_t)node * 64 + lane] + acc;
    }
}

// ===================== Edge layer 2 (CSR gather, 16->128) ===================
// Lane owns dims (2*lane, 2*lane+1); weight prologue = 16 coalesced float2
// loads from WeT2, once per 8 nodes.
__global__ __launch_bounds__(256, 4) void k_edge2(
    const int* __restrict__ rp, const int* __restrict__ srcs,
    const float* __restrict__ eaw,
    const float* __restrict__ WeT2, const float* __restrict__ be2,
    const float* __restrict__ h, float* __restrict__ out)
{
    const int lane = threadIdx.x & 63;
    const int wv = __builtin_amdgcn_readfirstlane(threadIdx.x >> 6);
    const int n0 = blockIdx.x * (4 * NPW) + wv * NPW;
    if (n0 >= N_NODES) return;

    const int dA = 2 * lane;
    float wrA[16], wrB[16];
#pragma unroll
    for (int k = 0; k < 16; ++k) {
        const float2 w = *(const float2*)(WeT2 + k * 128 + dA);  // coalesced 512B
        wrA[k] = w.x; wrB[k] = w.y;
    }
    const float2 bv = *(const float2*)(be2 + dA);
    const float biasA = bv.x, biasB = bv.y;

    for (int ni = 0; ni < NPW; ++ni) {
        const int node = n0 + ni;
        if (node >= N_NODES) break;
        const int beg = rp[node], end = rp[node + 1];            // s_load
        float accA = 0.f, accB = 0.f;

        if (beg < end) {
            int l16 = beg + (lane & 15);
            int sl = srcs[l16 < end ? l16 : end - 1];
            float4 ev = *(const float4*)(eaw + (size_t)beg * 16 + lane * 4);
            for (int c = beg; c < end; c += 16) {
                const int cp = (c + 16 < end) ? c + 16 : c;
                const int lp = cp + (lane & 15);
                const int sln = srcs[lp < end ? lp : end - 1];
                const float4 evn = *(const float4*)(eaw + (size_t)cp * 16 + lane * 4);
                const int n = end - c < 16 ? end - c : 16;
#pragma unroll 4
                for (int j = 0; j < n; ++j) {
                    const int src = __builtin_amdgcn_readlane(sl, j);
                    const float2 hv = *(const float2*)(h + (size_t)src * 128 + dA);
                    const int L = 4 * j;
                    const float e0  = __rlf(ev.x, L),     e1  = __rlf(ev.y, L);
                    const float e2  = __rlf(ev.z, L),     e3  = __rlf(ev.w, L);
                    const float e4  = __rlf(ev.x, L + 1), e5  = __rlf(ev.y, L + 1);
                    const float e6  = __rlf(ev.z, L + 1), e7  = __rlf(ev.w, L + 1);
                    const float e8  = __rlf(ev.x, L + 2), e9  = __rlf(ev.y, L + 2);
                    const float e10 = __rlf(ev.z, L + 2), e11 = __rlf(ev.w, L + 2);
                    const float e12 = __rlf(ev.x, L + 3), e13 = __rlf(ev.y, L + 3);
                    const float e14 = __rlf(ev.z, L + 3), e15 = __rlf(ev.w, L + 3);
                    float dA_ = biasA;
                    dA_ = fmaf(e0,  wrA[0],  dA_); dA_ = fmaf(e1,  wrA[1],  dA_);
                    dA_ = fmaf(e2,  wrA[2],  dA_); dA_ = fmaf(e3,  wrA[3],  dA_);
                    dA_ = fmaf(e4,  wrA[4],  dA_); dA_ = fmaf(e5,  wrA[5],  dA_);
                    dA_ = fmaf(e6,  wrA[6],  dA_); dA_ = fmaf(e7,  wrA[7],  dA_);
                    dA_ = fmaf(e8,  wrA[8],  dA_); dA_ = fmaf(e9,  wrA[9],  dA_);
                    dA_ = fmaf(e10, wrA[10], dA_); dA_ = fmaf(e11, wrA[11], dA_);
                    dA_ = fmaf(e12, wrA[12], dA_); dA_ = fmaf(e13, wrA[13], dA_);
                    dA_ = fmaf(e14, wrA[14], dA_); dA_ = fmaf(e15, wrA[15], dA_);
                    float dB_ = biasB;
                    dB_ = fmaf(e0,  wrB[0],  dB_); dB_ = fmaf(e1,  wrB[1],  dB_);
                    dB_ = fmaf(e2,  wrB[2],  dB_); dB_ = fmaf(e3,  wrB[3],  dB_);
                    dB_ = fmaf(e4,  wrB[4],  dB_); dB_ = fmaf(e5,  wrB[5],  dB_);
                    dB_ = fmaf(e6,  wrB[6],  dB_); dB_ = fmaf(e7,  wrB[7],  dB_);
                    dB_ = fmaf(e8,  wrB[8],  dB_); dB_ = fmaf(e9,  wrB[9],  dB_);
                    dB_ = fmaf(e10, wrB[10], dB_); dB_ = fmaf(e11, wrB[11], dB_);
                    dB_ = fmaf(e12, wrB[12], dB_); dB_ = fmaf(e13, wrB[13], dB_);
                    dB_ = fmaf(e14, wrB[14], dB_); dB_ = fmaf(e15, wrB[15], dB_);
                    accA += fmaxf(hv.x + dA_, 0.f);
                    accB += fmaxf(hv.y + dB_, 0.f);
                }
                sl = sln; ev = evn;
            }
        }
        const float2 self = *(const float2*)(h + (size_t)node * 128 + dA);
        *(float2*)(out + (size_t)node * 128 + dA) =
            make_float2(self.x + accA, self.y + accB);
    }
}

// ========================= Dense GEMM (node MLP) ============================
// OUT[n][j] = act( sum_k H[n][k]*WT[k][j] + b[j] ),  WT pre-transposed.
// Wave wv owns j = 32*wv..32*wv+31 (wave-uniform -> SGPR W row); lane owns
// nodes (lane, lane+64). LDS = transposed H tile only (66 KB -> 2 blocks/CU).
// In-place safe (H==OUT): block reads only rows [base, base+NT).
#define NT 128

template<int KIN, int JOUT, bool RELU>
__global__ __launch_bounds__(256) void k_mlp(
    const float* __restrict__ H, const float* __restrict__ WT,
    const float* __restrict__ b, float* __restrict__ OUT)
{
    extern __shared__ float hT[];          // [KIN][129]
    const int tid  = threadIdx.x;
    const int lane = tid & 63;
    const int wv   = __builtin_amdgcn_readfirstlane(tid >> 6);
    const int j0   = wv * 32;
    const int base = blockIdx.x * NT;

    for (int idx = tid; idx < NT * (KIN / 4); idx += 256) {
        const int q = idx & (KIN / 4 - 1);
        const int n = idx / (KIN / 4);
        const int ng = (base + n < N_NODES) ? (base + n) : (N_NODES - 1);
        const float4 v = *(const float4*)(H + (size_t)ng * KIN + 4 * q);
        hT[(4 * q + 0) * 129 + n] = v.x;
        hT[(4 * q + 1) * 129 + n] = v.y;
        hT[(4 * q + 2) * 129 + n] = v.z;
        hT[(4 * q + 3) * 129 + n] = v.w;
    }
    __syncthreads();

    float acc0[32], acc1[32];
#pragma unroll
    for (int m = 0; m < 32; ++m) { acc0[m] = 0.f; acc1[m] = 0.f; }

    float wc[32];
#pragma unroll
    for (int m = 0; m < 32; ++m) wc[m] = WT[j0 + m];
    float h0 = hT[lane], h1 = hT[lane + 64];

    for (int k = 0; k < KIN - 1; ++k) {
        float wn[32];
#pragma unroll
        for (int m = 0; m < 32; ++m) wn[m] = WT[(k + 1) * 128 + j0 + m];
        const float h0n = hT[(k + 1) * 129 + lane];
        const float h1n = hT[(k + 1) * 129 + lane + 64];
#pragma unroll
        for (int m = 0; m < 32; ++m) {
            acc0[m] = fmaf(h0, wc[m], acc0[m]);
            acc1[m] = fmaf(h1, wc[m], acc1[m]);
        }
#pragma unroll
        for (int m = 0; m < 32; ++m) wc[m] = wn[m];
        h0 = h0n; h1 = h1n;
    }
#pragma unroll
    for (int m = 0; m < 32; ++m) {
        acc0[m] = fmaf(h0, wc[m], acc0[m]);
        acc1[m] = fmaf(h1, wc[m], acc1[m]);
    }

    float bv[32];
#pragma unroll
    for (int m = 0; m < 32; ++m) bv[m] = (j0 + m < JOUT) ? b[j0 + m] : 0.f;

    const int n0 = base + lane, n1 = base + lane + 64;
    if (n0 < N_NODES) {
        float* row = OUT + (size_t)n0 * JOUT;
#pragma unroll
        for (int g = 0; g < 8; ++g) {
            if (j0 + 4 * g < JOUT) {
                float4 v;
                v.x = acc0[4 * g + 0] + bv[4 * g + 0];
                v.y = acc0[4 * g + 1] + bv[4 * g + 1];
                v.z = acc0[4 * g + 2] + bv[4 * g + 2];
                v.w = acc0[4 * g + 3] + bv[4 * g + 3];
                if (RELU) {
                    v.x = fmaxf(v.x, 0.f); v.y = fmaxf(v.y, 0.f);
                    v.z = fmaxf(v.z, 0.f); v.w = fmaxf(v.w, 0.f);
                }
                *(float4*)(row + j0 + 4 * g) = v;
            }
        }
    }
    if (n1 < N_NODES) {
        float* row = OUT + (size_t)n1 * JOUT;
#pragma unroll
        for (int g = 0; g < 8; ++g) {
            if (j0 + 4 * g < JOUT) {
                float4 v;
                v.x = acc1[4 * g + 0] + bv[4 * g + 0];
                v.y = acc1[4 * g + 1] + bv[4 * g + 1];
                v.z = acc1[4 * g + 2] + bv[4 * g + 2];
                v.w = acc1[4 * g + 3] + bv[4 * g + 3];
                if (RELU) {
                    v.x = fmaxf(v.x, 0.f); v.y = fmaxf(v.y, 0.f);
                    v.z = fmaxf(v.z, 0.f); v.w = fmaxf(v.w, 0.f);
                }
                *(float4*)(row + j0 + 4 * g) = v;
            }
        }
    }
}

// ============================================================================
// Workspace layout (peak 106,116,096 B), lifetimes packed:
//   [0,        204800)  rowptr            (build .. edge2)
//   [204800,  3404800)  srcs              (prep .. edge2)
//       cnt    @204800  (hist..scan, dead before srcs written)
//       cursor @409600  (scan..scatter, dead before srcs written)
//   [3404800, 54604800) eaw  51.2MB       (prep .. edge2)
//     NOTE: edge kernels may over-read up to 1KB past a row's end (chunk
//     granularity); bytes land in t1 region (allocated), values unused.
//   [54604800,80204800) t1 (=h1) 25.6MB   (mlp11 .. edge2-in)
//       pairs @54604800 6.4MB             (scatter..prep, dead before t1)
//   [80204800,105804800) h2pre 25.6MB     (edge2-out .. head, in-place MLPs)
//       h1pre @80204800 12.8MB            (edge1..mlp11, dead before h2pre)
//   [105804800,106116096) WT 311,296 B    (k_wt .. head; incl WeT1/WeT2)
extern "C" void kernel_launch(void* const* d_in, const int* in_sizes, int n_in,
                              void* d_out, int out_size, void* d_ws, size_t ws_size,
                              hipStream_t stream) {
    const float* x     = (const float*)d_in[0];
    const int*   ei    = (const int*)  d_in[1];
    const float* eattr = (const float*)d_in[2];
    const float* ew    = (const float*)d_in[3];
    const float* We1   = (const float*)d_in[4];
    const float* be1   = (const float*)d_in[5];
    const float* W11   = (const float*)d_in[6];
    const float* b11   = (const float*)d_in[7];
    const float* W12   = (const float*)d_in[8];
    const float* b12   = (const float*)d_in[9];
    const float* We2   = (const float*)d_in[10];
    const float* be2   = (const float*)d_in[11];
    const float* W21   = (const float*)d_in[12];
    const float* b21   = (const float*)d_in[13];
    const float* W22   = (const float*)d_in[14];
    const float* b22   = (const float*)d_in[15];
    const float* Wo    = (const float*)d_in[16];
    const float* bo    = (const float*)d_in[17];
    float* out = (float*)d_out;

    char* ws = (char*)d_ws;
    int*   rowptr = (int*)  (ws + 0);
    int*   cnt    = (int*)  (ws + 204800);
    int*   cursor = (int*)  (ws + 409600);
    int*   srcs   = (int*)  (ws + 204800);     // overlays cnt+cursor (dead)
    float* eaw    = (float*)(ws + 3404800);    // 51.2 MB
    float* t1     = (float*)(ws + 54604800);   // 25.6 MB (h1 alias)
    int2*  pairs  = (int2*) (ws + 54604800);   // 6.4 MB, dead before t1 written
    float* h2pre  = (float*)(ws + 80204800);   // 25.6 MB
    float* h1pre  = (float*)(ws + 80204800);   // 12.8 MB, dead before h2pre
    float* WT     = (float*)(ws + 105804800);  // 311,296 B
    float* WT11 = WT;           // [64][128]
    float* WT12 = WT + 8192;    // [128][128]
    float* WT21 = WT + 24576;
    float* WT22 = WT + 40960;
    float* WTo  = WT + 57344;   // [128][128] zero-padded j>=100
    float* WeT1 = WT + 73728;   // [16][64]
    float* WeT2 = WT + 74752;   // [16][128]

    hipMemsetAsync(cnt, 0, 200000, stream);

    k_wt<<<300, 256, 0, stream>>>(W11, W12, W21, W22, Wo, We1, We2, WT);

    const int EB = (E_EDGES + 255) / 256;      // 3125
    k_hist<<<EB, 256, 0, stream>>>(ei, cnt);
    k_scan<<<1, 1024, 0, stream>>>(cnt, rowptr, cursor);
    k_scatter<<<EB, 256, 0, stream>>>(ei, cursor, pairs);

    const int PB = (E_EDGES * 4 + 255) / 256;  // 12500
    k_prep<<<PB, 256, 0, stream>>>(pairs, eattr, ew, eaw, srcs);

    const int NB = (N_NODES + 4 * NPW - 1) / (4 * NPW);  // 1563
    k_edge1<<<NB, 256, 0, stream>>>(rowptr, srcs, eaw, WeT1, be1, x, h1pre);

    const int TILES = (N_NODES + NT - 1) / NT;          // 391
    const size_t lds64  = (size_t)(64  * 129) * 4;      // 33,024 B
    const size_t lds128 = (size_t)(128 * 129) * 4;      // 66,048 B

    k_mlp<64, 128, true><<<TILES, 256, lds64, stream>>>(h1pre, WT11, b11, t1);
    k_mlp<128, 128, true><<<TILES, 256, lds128, stream>>>(t1, WT12, b12, t1);

    k_edge2<<<NB, 256, 0, stream>>>(rowptr, srcs, eaw, WeT2, be2, t1, h2pre);

    k_mlp<128, 128, true><<<TILES, 256, lds128, stream>>>(h2pre, WT21, b21, h2pre);
    k_mlp<128, 128, true><<<TILES, 256, lds128, stream>>>(h2pre, WT22, b22, h2pre);
    k_mlp<128, 100, false><<<TILES, 256, lds128, stream>>>(h2pre, WTo, bo, out);
}

// Round 5
// 733.213 us; speedup vs baseline: 1.0752x; 1.0752x over previous
//
#include <hip/hip_runtime.h>

#define N_NODES 50000
#define E_EDGES 800000

__device__ __forceinline__ float __rlf(float v, int l) {
    return __int_as_float(__builtin_amdgcn_readlane(__float_as_int(v), l));
}

// ============================ CSR build =====================================
__global__ __launch_bounds__(256) void k_hist(
    const int* __restrict__ ei, int* __restrict__ cnt)
{
    const int e = blockIdx.x * 256 + threadIdx.x;
    if (e < E_EDGES) atomicAdd(&cnt[ei[E_EDGES + e]], 1);
}

// single block, 1024 threads: exclusive prefix over cnt -> rowptr, cursor
__global__ __launch_bounds__(1024) void k_scan(
    const int* __restrict__ cnt, int* __restrict__ rowptr, int* __restrict__ cursor)
{
    __shared__ int part[1024];
    const int tid = threadIdx.x;
    const int CH = 49;                      // 1024*49 >= 50000
    const int base = tid * CH;
    int sum = 0;
    for (int c = 0; c < CH; ++c) {
        const int i = base + c;
        if (i < N_NODES) sum += cnt[i];
    }
    part[tid] = sum;
    __syncthreads();
    for (int off = 1; off < 1024; off <<= 1) {
        int v = part[tid];
        int u = (tid >= off) ? part[tid - off] : 0;
        __syncthreads();
        part[tid] = v + u;
        __syncthreads();
    }
    int run = (tid > 0) ? part[tid - 1] : 0;
    for (int c = 0; c < CH; ++c) {
        const int i = base + c;
        if (i < N_NODES) {
            rowptr[i] = run;
            cursor[i] = run;
            run += cnt[i];
        }
    }
    if (tid == 1023) rowptr[N_NODES] = part[1023];
}

__global__ __launch_bounds__(256) void k_scatter(
    const int* __restrict__ ei, int* __restrict__ cursor, int2* __restrict__ pairs)
{
    const int e = blockIdx.x * 256 + threadIdx.x;
    if (e < E_EDGES) {
        const int dst = ei[E_EDGES + e];
        const int pos = atomicAdd(&cursor[dst], 1);
        pairs[pos] = make_int2(ei[e], e);
    }
}

// ============ CSR-order edge-attr pre-scale (kills gather deps) =============
__global__ __launch_bounds__(256) void k_prep(
    const int2* __restrict__ pairs, const float* __restrict__ eattr,
    const float* __restrict__ ew, float* __restrict__ eaw, int* __restrict__ srcs)
{
    const int t = blockIdx.x * 256 + threadIdx.x;
    const int pos = t >> 2;
    if (pos >= E_EDGES) return;
    const int q = t & 3;
    const int2 p = pairs[pos];
    if (q == 0) srcs[pos] = p.x;
    const float w = ew[p.y];
    const float4 a = *((const float4*)(eattr + (size_t)p.y * 16) + q);
    *((float4*)(eaw + (size_t)pos * 16) + q) =
        make_float4(a.x * w, a.y * w, a.z * w, a.w * w);
}

// ================== Weight transposes (once, tiny) ==========================
// WT segments (float offsets): WT11@0 [64][128], WT12@8192 [128][128],
// WT21@24576, WT22@40960, WTo@57344 [128][128] (j>=100 zero-padded),
// WeT1@73728 [16][64], WeT2@74752 [16][128].
__global__ __launch_bounds__(256) void k_wt(
    const float* __restrict__ W11, const float* __restrict__ W12,
    const float* __restrict__ W21, const float* __restrict__ W22,
    const float* __restrict__ Wo,
    const float* __restrict__ We1, const float* __restrict__ We2,
    float* __restrict__ WT)
{
    const int bid = blockIdx.x;
    const int tid = threadIdx.x;
    if (bid < 288) {
        const float* src; int KIN, JOUT, lbase, obase;
        if (bid < 32)       { src = W11; KIN = 64;  JOUT = 128; lbase = 0;   obase = 0; }
        else if (bid < 96)  { src = W12; KIN = 128; JOUT = 128; lbase = 32;  obase = 8192; }
        else if (bid < 160) { src = W21; KIN = 128; JOUT = 128; lbase = 96;  obase = 24576; }
        else if (bid < 224) { src = W22; KIN = 128; JOUT = 128; lbase = 160; obase = 40960; }
        else                { src = Wo;  KIN = 128; JOUT = 100; lbase = 224; obase = 57344; }
        const int idx = (bid - lbase) * 256 + tid;   // < KIN*128
        const int k = idx >> 7, j = idx & 127;
        WT[obase + idx] = (j < JOUT) ? src[j * KIN + k] : 0.f;
    } else if (bid < 292) {                   // WeT1[k][d] = We1[d][k]
        const int idx = (bid - 288) * 256 + tid;     // < 1024
        const int k = idx >> 6, d = idx & 63;
        WT[73728 + idx] = We1[d * 16 + k];
    } else {                                  // WeT2[k][d] = We2[d][k]
        const int idx = (bid - 292) * 256 + tid;     // < 2048
        const int k = idx >> 7, d = idx & 127;
        WT[74752 + idx] = We2[d * 16 + k];
    }
}

// ===================== Edge layer 1 (CSR gather, 16->64) ====================
// One wave per node (50k waves: machine stays full). Weight prologue is now
// COALESCED (WeT1: 16x 256B loads, was 16x 64-distinct-line gathers).
// Inner loop: chunk-broadcast (1 coalesced float4/lane per 16 edges,
// readlane -> SGPR), chained bias-seeded FMA, next-chunk prefetch.
__global__ __launch_bounds__(256, 4) void k_edge1(
    const int* __restrict__ rp, const int* __restrict__ srcs,
    const float* __restrict__ eaw,
    const float* __restrict__ WeT1, const float* __restrict__ be1,
    const float* __restrict__ x, float* __restrict__ out)
{
    const int lane = threadIdx.x & 63;
    const int node = blockIdx.x * 4 + (threadIdx.x >> 6);
    if (node >= N_NODES) return;

    float wr[16];
#pragma unroll
    for (int k = 0; k < 16; ++k) wr[k] = WeT1[k * 64 + lane];   // coalesced 256B
    const float bias = be1[lane];

    const int beg = rp[node], end = rp[node + 1];
    float acc = 0.f;

    if (beg < end) {
        int l16 = beg + (lane & 15);
        int sl = srcs[l16 < end ? l16 : end - 1];
        float4 ev = *(const float4*)(eaw + (size_t)beg * 16 + lane * 4);
        for (int c = beg; c < end; c += 16) {
            const int cp = (c + 16 < end) ? c + 16 : c;      // prefetch chunk
            const int lp = cp + (lane & 15);
            const int sln = srcs[lp < end ? lp : end - 1];
            const float4 evn = *(const float4*)(eaw + (size_t)cp * 16 + lane * 4);
            const int n = end - c < 16 ? end - c : 16;       // uniform per wave
#pragma unroll 8
            for (int j = 0; j < n; ++j) {
                const int src = __builtin_amdgcn_readlane(sl, j);
                const float hv = x[(size_t)src * 64 + lane];
                const int L = 4 * j;
                float d = bias;
                d = fmaf(__rlf(ev.x, L),     wr[0],  d);
                d = fmaf(__rlf(ev.y, L),     wr[1],  d);
                d = fmaf(__rlf(ev.z, L),     wr[2],  d);
                d = fmaf(__rlf(ev.w, L),     wr[3],  d);
                d = fmaf(__rlf(ev.x, L + 1), wr[4],  d);
                d = fmaf(__rlf(ev.y, L + 1), wr[5],  d);
                d = fmaf(__rlf(ev.z, L + 1), wr[6],  d);
                d = fmaf(__rlf(ev.w, L + 1), wr[7],  d);
                d = fmaf(__rlf(ev.x, L + 2), wr[8],  d);
                d = fmaf(__rlf(ev.y, L + 2), wr[9],  d);
                d = fmaf(__rlf(ev.z, L + 2), wr[10], d);
                d = fmaf(__rlf(ev.w, L + 2), wr[11], d);
                d = fmaf(__rlf(ev.x, L + 3), wr[12], d);
                d = fmaf(__rlf(ev.y, L + 3), wr[13], d);
                d = fmaf(__rlf(ev.z, L + 3), wr[14], d);
                d = fmaf(__rlf(ev.w, L + 3), wr[15], d);
                acc += fmaxf(hv + d, 0.f);
            }
            sl = sln; ev = evn;
        }
    }
    out[(size_t)node * 64 + lane] = x[(size_t)node * 64 + lane] + acc;
}

// ===================== Edge layer 2 (CSR gather, 16->128) ===================
// One wave per node; lane owns dims (2*lane, 2*lane+1); coalesced WeT2
// prologue (16x 512B float2 loads).
__global__ __launch_bounds__(256, 4) void k_edge2(
    const int* __restrict__ rp, const int* __restrict__ srcs,
    const float* __restrict__ eaw,
    const float* __restrict__ WeT2, const float* __restrict__ be2,
    const float* __restrict__ h, float* __restrict__ out)
{
    const int lane = threadIdx.x & 63;
    const int node = blockIdx.x * 4 + (threadIdx.x >> 6);
    if (node >= N_NODES) return;

    const int dA = 2 * lane;
    float wrA[16], wrB[16];
#pragma unroll
    for (int k = 0; k < 16; ++k) {
        const float2 w = *(const float2*)(WeT2 + k * 128 + dA);  // coalesced 512B
        wrA[k] = w.x; wrB[k] = w.y;
    }
    const float2 bv = *(const float2*)(be2 + dA);
    const float biasA = bv.x, biasB = bv.y;

    const int beg = rp[node], end = rp[node + 1];
    float accA = 0.f, accB = 0.f;

    if (beg < end) {
        int l16 = beg + (lane & 15);
        int sl = srcs[l16 < end ? l16 : end - 1];
        float4 ev = *(const float4*)(eaw + (size_t)beg * 16 + lane * 4);
        for (int c = beg; c < end; c += 16) {
            const int cp = (c + 16 < end) ? c + 16 : c;
            const int lp = cp + (lane & 15);
            const int sln = srcs[lp < end ? lp : end - 1];
            const float4 evn = *(const float4*)(eaw + (size_t)cp * 16 + lane * 4);
            const int n = end - c < 16 ? end - c : 16;
#pragma unroll 4
            for (int j = 0; j < n; ++j) {
                const int src = __builtin_amdgcn_readlane(sl, j);
                const float2 hv = *(const float2*)(h + (size_t)src * 128 + dA);
                const int L = 4 * j;
                const float e0  = __rlf(ev.x, L),     e1  = __rlf(ev.y, L);
                const float e2  = __rlf(ev.z, L),     e3  = __rlf(ev.w, L);
                const float e4  = __rlf(ev.x, L + 1), e5  = __rlf(ev.y, L + 1);
                const float e6  = __rlf(ev.z, L + 1), e7  = __rlf(ev.w, L + 1);
                const float e8  = __rlf(ev.x, L + 2), e9  = __rlf(ev.y, L + 2);
                const float e10 = __rlf(ev.z, L + 2), e11 = __rlf(ev.w, L + 2);
                const float e12 = __rlf(ev.x, L + 3), e13 = __rlf(ev.y, L + 3);
                const float e14 = __rlf(ev.z, L + 3), e15 = __rlf(ev.w, L + 3);
                float dA_ = biasA;
                dA_ = fmaf(e0,  wrA[0],  dA_); dA_ = fmaf(e1,  wrA[1],  dA_);
                dA_ = fmaf(e2,  wrA[2],  dA_); dA_ = fmaf(e3,  wrA[3],  dA_);
                dA_ = fmaf(e4,  wrA[4],  dA_); dA_ = fmaf(e5,  wrA[5],  dA_);
                dA_ = fmaf(e6,  wrA[6],  dA_); dA_ = fmaf(e7,  wrA[7],  dA_);
                dA_ = fmaf(e8,  wrA[8],  dA_); dA_ = fmaf(e9,  wrA[9],  dA_);
                dA_ = fmaf(e10, wrA[10], dA_); dA_ = fmaf(e11, wrA[11], dA_);
                dA_ = fmaf(e12, wrA[12], dA_); dA_ = fmaf(e13, wrA[13], dA_);
                dA_ = fmaf(e14, wrA[14], dA_); dA_ = fmaf(e15, wrA[15], dA_);
                float dB_ = biasB;
                dB_ = fmaf(e0,  wrB[0],  dB_); dB_ = fmaf(e1,  wrB[1],  dB_);
                dB_ = fmaf(e2,  wrB[2],  dB_); dB_ = fmaf(e3,  wrB[3],  dB_);
                dB_ = fmaf(e4,  wrB[4],  dB_); dB_ = fmaf(e5,  wrB[5],  dB_);
                dB_ = fmaf(e6,  wrB[6],  dB_); dB_ = fmaf(e7,  wrB[7],  dB_);
                dB_ = fmaf(e8,  wrB[8],  dB_); dB_ = fmaf(e9,  wrB[9],  dB_);
                dB_ = fmaf(e10, wrB[10], dB_); dB_ = fmaf(e11, wrB[11], dB_);
                dB_ = fmaf(e12, wrB[12], dB_); dB_ = fmaf(e13, wrB[13], dB_);
                dB_ = fmaf(e14, wrB[14], dB_); dB_ = fmaf(e15, wrB[15], dB_);
                accA += fmaxf(hv.x + dA_, 0.f);
                accB += fmaxf(hv.y + dB_, 0.f);
            }
            sl = sln; ev = evn;
        }
    }
    const float2 self = *(const float2*)(h + (size_t)node * 128 + dA);
    *(float2*)(out + (size_t)node * 128 + dA) =
        make_float2(self.x + accA, self.y + accB);
}

// ========================= Dense GEMM (node MLP) ============================
// OUT[n][j] = act( sum_k H[n][k]*WT[k][j] + b[j] ),  WT pre-transposed.
// Wave wv owns j = 32*wv..32*wv+31 (wave-uniform -> SGPR W row); lane owns
// nodes (lane, lane+64). LDS = transposed H tile only (66 KB -> 2 blocks/CU).
// In-place safe (H==OUT): block reads only rows [base, base+NT).
#define NT 128

template<int KIN, int JOUT, bool RELU>
__global__ __launch_bounds__(256) void k_mlp(
    const float* __restrict__ H, const float* __restrict__ WT,
    const float* __restrict__ b, float* __restrict__ OUT)
{
    extern __shared__ float hT[];          // [KIN][129]
    const int tid  = threadIdx.x;
    const int lane = tid & 63;
    const int wv   = __builtin_amdgcn_readfirstlane(tid >> 6);
    const int j0   = wv * 32;
    const int base = blockIdx.x * NT;

    for (int idx = tid; idx < NT * (KIN / 4); idx += 256) {
        const int q = idx & (KIN / 4 - 1);
        const int n = idx / (KIN / 4);
        const int ng = (base + n < N_NODES) ? (base + n) : (N_NODES - 1);
        const float4 v = *(const float4*)(H + (size_t)ng * KIN + 4 * q);
        hT[(4 * q + 0) * 129 + n] = v.x;
        hT[(4 * q + 1) * 129 + n] = v.y;
        hT[(4 * q + 2) * 129 + n] = v.z;
        hT[(4 * q + 3) * 129 + n] = v.w;
    }
    __syncthreads();

    float acc0[32], acc1[32];
#pragma unroll
    for (int m = 0; m < 32; ++m) { acc0[m] = 0.f; acc1[m] = 0.f; }

    float wc[32];
#pragma unroll
    for (int m = 0; m < 32; ++m) wc[m] = WT[j0 + m];
    float h0 = hT[lane], h1 = hT[lane + 64];

    for (int k = 0; k < KIN - 1; ++k) {
        float wn[32];
#pragma unroll
        for (int m = 0; m < 32; ++m) wn[m] = WT[(k + 1) * 128 + j0 + m];
        const float h0n = hT[(k + 1) * 129 + lane];
        const float h1n = hT[(k + 1) * 129 + lane + 64];
#pragma unroll
        for (int m = 0; m < 32; ++m) {
            acc0[m] = fmaf(h0, wc[m], acc0[m]);
            acc1[m] = fmaf(h1, wc[m], acc1[m]);
        }
#pragma unroll
        for (int m = 0; m < 32; ++m) wc[m] = wn[m];
        h0 = h0n; h1 = h1n;
    }
#pragma unroll
    for (int m = 0; m < 32; ++m) {
        acc0[m] = fmaf(h0, wc[m], acc0[m]);
        acc1[m] = fmaf(h1, wc[m], acc1[m]);
    }

    float bv[32];
#pragma unroll
    for (int m = 0; m < 32; ++m) bv[m] = (j0 + m < JOUT) ? b[j0 + m] : 0.f;

    const int n0 = base + lane, n1 = base + lane + 64;
    if (n0 < N_NODES) {
        float* row = OUT + (size_t)n0 * JOUT;
#pragma unroll
        for (int g = 0; g < 8; ++g) {
            if (j0 + 4 * g < JOUT) {
                float4 v;
                v.x = acc0[4 * g + 0] + bv[4 * g + 0];
                v.y = acc0[4 * g + 1] + bv[4 * g + 1];
                v.z = acc0[4 * g + 2] + bv[4 * g + 2];
                v.w = acc0[4 * g + 3] + bv[4 * g + 3];
                if (RELU) {
                    v.x = fmaxf(v.x, 0.f); v.y = fmaxf(v.y, 0.f);
                    v.z = fmaxf(v.z, 0.f); v.w = fmaxf(v.w, 0.f);
                }
                *(float4*)(row + j0 + 4 * g) = v;
            }
        }
    }
    if (n1 < N_NODES) {
        float* row = OUT + (size_t)n1 * JOUT;
#pragma unroll
        for (int g = 0; g < 8; ++g) {
            if (j0 + 4 * g < JOUT) {
                float4 v;
                v.x = acc1[4 * g + 0] + bv[4 * g + 0];
                v.y = acc1[4 * g + 1] + bv[4 * g + 1];
                v.z = acc1[4 * g + 2] + bv[4 * g + 2];
                v.w = acc1[4 * g + 3] + bv[4 * g + 3];
                if (RELU) {
                    v.x = fmaxf(v.x, 0.f); v.y = fmaxf(v.y, 0.f);
                    v.z = fmaxf(v.z, 0.f); v.w = fmaxf(v.w, 0.f);
                }
                *(float4*)(row + j0 + 4 * g) = v;
            }
        }
    }
}

// ============================================================================
// Workspace layout (peak 106,116,096 B), lifetimes packed:
//   [0,        204800)  rowptr            (build .. edge2)
//   [204800,  3404800)  srcs              (prep .. edge2)
//       cnt    @204800  (hist..scan, dead before srcs written)
//       cursor @409600  (scan..scatter, dead before srcs written)
//   [3404800, 54604800) eaw  51.2MB       (prep .. edge2)
//     NOTE: edge kernels may over-read up to 1KB past a row's end (chunk
//     granularity); bytes land in t1 region (allocated), values unused.
//   [54604800,80204800) t1 (=h1) 25.6MB   (mlp11 .. edge2-in)
//       pairs @54604800 6.4MB             (scatter..prep, dead before t1)
//   [80204800,105804800) h2pre 25.6MB     (edge2-out .. head, in-place MLPs)
//       h1pre @80204800 12.8MB            (edge1..mlp11, dead before h2pre)
//   [105804800,106116096) WT 311,296 B    (k_wt .. head; incl WeT1/WeT2)
extern "C" void kernel_launch(void* const* d_in, const int* in_sizes, int n_in,
                              void* d_out, int out_size, void* d_ws, size_t ws_size,
                              hipStream_t stream) {
    const float* x     = (const float*)d_in[0];
    const int*   ei    = (const int*)  d_in[1];
    const float* eattr = (const float*)d_in[2];
    const float* ew    = (const float*)d_in[3];
    const float* We1   = (const float*)d_in[4];
    const float* be1   = (const float*)d_in[5];
    const float* W11   = (const float*)d_in[6];
    const float* b11   = (const float*)d_in[7];
    const float* W12   = (const float*)d_in[8];
    const float* b12   = (const float*)d_in[9];
    const float* We2   = (const float*)d_in[10];
    const float* be2   = (const float*)d_in[11];
    const float* W21   = (const float*)d_in[12];
    const float* b21   = (const float*)d_in[13];
    const float* W22   = (const float*)d_in[14];
    const float* b22   = (const float*)d_in[15];
    const float* Wo    = (const float*)d_in[16];
    const float* bo    = (const float*)d_in[17];
    float* out = (float*)d_out;

    char* ws = (char*)d_ws;
    int*   rowptr = (int*)  (ws + 0);
    int*   cnt    = (int*)  (ws + 204800);
    int*   cursor = (int*)  (ws + 409600);
    int*   srcs   = (int*)  (ws + 204800);     // overlays cnt+cursor (dead)
    float* eaw    = (float*)(ws + 3404800);    // 51.2 MB
    float* t1     = (float*)(ws + 54604800);   // 25.6 MB (h1 alias)
    int2*  pairs  = (int2*) (ws + 54604800);   // 6.4 MB, dead before t1 written
    float* h2pre  = (float*)(ws + 80204800);   // 25.6 MB
    float* h1pre  = (float*)(ws + 80204800);   // 12.8 MB, dead before h2pre
    float* WT     = (float*)(ws + 105804800);  // 311,296 B
    float* WT11 = WT;           // [64][128]
    float* WT12 = WT + 8192;    // [128][128]
    float* WT21 = WT + 24576;
    float* WT22 = WT + 40960;
    float* WTo  = WT + 57344;   // [128][128] zero-padded j>=100
    float* WeT1 = WT + 73728;   // [16][64]
    float* WeT2 = WT + 74752;   // [16][128]

    hipMemsetAsync(cnt, 0, 200000, stream);

    k_wt<<<300, 256, 0, stream>>>(W11, W12, W21, W22, Wo, We1, We2, WT);

    const int EB = (E_EDGES + 255) / 256;      // 3125
    k_hist<<<EB, 256, 0, stream>>>(ei, cnt);
    k_scan<<<1, 1024, 0, stream>>>(cnt, rowptr, cursor);
    k_scatter<<<EB, 256, 0, stream>>>(ei, cursor, pairs);

    const int PB = (E_EDGES * 4 + 255) / 256;  // 12500
    k_prep<<<PB, 256, 0, stream>>>(pairs, eattr, ew, eaw, srcs);

    const int NB = (N_NODES + 3) / 4;          // 12500 (one wave per node)
    k_edge1<<<NB, 256, 0, stream>>>(rowptr, srcs, eaw, WeT1, be1, x, h1pre);

    const int TILES = (N_NODES + NT - 1) / NT;          // 391
    const size_t lds64  = (size_t)(64  * 129) * 4;      // 33,024 B
    const size_t lds128 = (size_t)(128 * 129) * 4;      // 66,048 B

    k_mlp<64, 128, true><<<TILES, 256, lds64, stream>>>(h1pre, WT11, b11, t1);
    k_mlp<128, 128, true><<<TILES, 256, lds128, stream>>>(t1, WT12, b12, t1);

    k_edge2<<<NB, 256, 0, stream>>>(rowptr, srcs, eaw, WeT2, be2, t1, h2pre);

    k_mlp<128, 128, true><<<TILES, 256, lds128, stream>>>(h2pre, WT21, b21, h2pre);
    k_mlp<128, 128, true><<<TILES, 256, lds128, stream>>>(h2pre, WT22, b22, h2pre);
    k_mlp<128, 100, false><<<TILES, 256, lds128, stream>>>(h2pre, WTo, bo, out);
}

// Round 6
// 620.310 us; speedup vs baseline: 1.2709x; 1.1820x over previous
//
#include <hip/hip_runtime.h>

#define N_NODES 50000
#define E_EDGES 800000
#define SCAN_NB 196   // 196*256 = 50176 >= N_NODES

__device__ __forceinline__ float __rlf(float v, int l) {
    return __int_as_float(__builtin_amdgcn_readlane(__float_as_int(v), l));
}

// ============================ CSR build =====================================
__global__ __launch_bounds__(256) void k_hist(
    const int* __restrict__ ei, int* __restrict__ cnt)
{
    const int e = blockIdx.x * 256 + threadIdx.x;
    if (e < E_EDGES) atomicAdd(&cnt[ei[E_EDGES + e]], 1);
}

// ---- two-level parallel exclusive scan (replaces 125us single-block scan) --
__global__ __launch_bounds__(256) void k_scan1(
    const int* __restrict__ cnt, int* __restrict__ bsum)
{
    __shared__ int red[256];
    const int tid = threadIdx.x;
    const int i = blockIdx.x * 256 + tid;
    red[tid] = (i < N_NODES) ? cnt[i] : 0;
    __syncthreads();
    for (int off = 128; off > 0; off >>= 1) {
        if (tid < off) red[tid] += red[tid + off];
        __syncthreads();
    }
    if (tid == 0) bsum[blockIdx.x] = red[0];
}

__global__ __launch_bounds__(256) void k_scan2(
    const int* __restrict__ bsum, int* __restrict__ boff)
{
    __shared__ int part[256];
    const int tid = threadIdx.x;
    const int v = (tid < SCAN_NB) ? bsum[tid] : 0;
    part[tid] = v;
    __syncthreads();
    for (int off = 1; off < 256; off <<= 1) {
        const int vv = part[tid];
        const int u = (tid >= off) ? part[tid - off] : 0;
        __syncthreads();
        part[tid] = vv + u;
        __syncthreads();
    }
    if (tid < SCAN_NB) boff[tid] = part[tid] - v;   // exclusive block offset
}

__global__ __launch_bounds__(256) void k_scan3(
    const int* __restrict__ cnt, const int* __restrict__ boff,
    int* __restrict__ rowptr, int* __restrict__ cursor)
{
    __shared__ int part[256];
    const int tid = threadIdx.x;
    const int i = blockIdx.x * 256 + tid;
    const int v = (i < N_NODES) ? cnt[i] : 0;
    part[tid] = v;
    __syncthreads();
    for (int off = 1; off < 256; off <<= 1) {
        const int vv = part[tid];
        const int u = (tid >= off) ? part[tid - off] : 0;
        __syncthreads();
        part[tid] = vv + u;
        __syncthreads();
    }
    const int excl = part[tid] - v + boff[blockIdx.x];
    if (i < N_NODES) { rowptr[i] = excl; cursor[i] = excl; }
    if (i == N_NODES) rowptr[N_NODES] = excl;  // beyond-end v=0 => excl = total
}

__global__ __launch_bounds__(256) void k_scatter(
    const int* __restrict__ ei, int* __restrict__ cursor, int2* __restrict__ pairs)
{
    const int e = blockIdx.x * 256 + threadIdx.x;
    if (e < E_EDGES) {
        const int dst = ei[E_EDGES + e];
        const int pos = atomicAdd(&cursor[dst], 1);
        pairs[pos] = make_int2(ei[e], e);
    }
}

// ============ CSR-order edge-attr pre-scale (kills gather deps) =============
__global__ __launch_bounds__(256) void k_prep(
    const int2* __restrict__ pairs, const float* __restrict__ eattr,
    const float* __restrict__ ew, float* __restrict__ eaw, int* __restrict__ srcs)
{
    const int t = blockIdx.x * 256 + threadIdx.x;
    const int pos = t >> 2;
    if (pos >= E_EDGES) return;
    const int q = t & 3;
    const int2 p = pairs[pos];
    if (q == 0) srcs[pos] = p.x;
    const float w = ew[p.y];
    const float4 a = *((const float4*)(eattr + (size_t)p.y * 16) + q);
    *((float4*)(eaw + (size_t)pos * 16) + q) =
        make_float4(a.x * w, a.y * w, a.z * w, a.w * w);
}

// ================== Weight transposes (once, tiny) ==========================
// WT segments (float offsets): WT11@0 [64][128], WT12@8192 [128][128],
// WT21@24576, WT22@40960, WTo@57344 [128][128] (j>=100 zero-padded),
// WeT1@73728 [16][64], WeT2@74752 [16][128].
__global__ __launch_bounds__(256) void k_wt(
    const float* __restrict__ W11, const float* __restrict__ W12,
    const float* __restrict__ W21, const float* __restrict__ W22,
    const float* __restrict__ Wo,
    const float* __restrict__ We1, const float* __restrict__ We2,
    float* __restrict__ WT)
{
    const int bid = blockIdx.x;
    const int tid = threadIdx.x;
    if (bid < 288) {
        const float* src; int KIN, JOUT, lbase, obase;
        if (bid < 32)       { src = W11; KIN = 64;  JOUT = 128; lbase = 0;   obase = 0; }
        else if (bid < 96)  { src = W12; KIN = 128; JOUT = 128; lbase = 32;  obase = 8192; }
        else if (bid < 160) { src = W21; KIN = 128; JOUT = 128; lbase = 96;  obase = 24576; }
        else if (bid < 224) { src = W22; KIN = 128; JOUT = 128; lbase = 160; obase = 40960; }
        else                { src = Wo;  KIN = 128; JOUT = 100; lbase = 224; obase = 57344; }
        const int idx = (bid - lbase) * 256 + tid;   // < KIN*128
        const int k = idx >> 7, j = idx & 127;
        WT[obase + idx] = (j < JOUT) ? src[j * KIN + k] : 0.f;
    } else if (bid < 292) {                   // WeT1[k][d] = We1[d][k]
        const int idx = (bid - 288) * 256 + tid;     // < 1024
        const int k = idx >> 6, d = idx & 63;
        WT[73728 + idx] = We1[d * 16 + k];
    } else {                                  // WeT2[k][d] = We2[d][k]
        const int idx = (bid - 292) * 256 + tid;     // < 2048
        const int k = idx >> 7, d = idx & 127;
        WT[74752 + idx] = We2[d * 16 + k];
    }
}

// ===================== Edge layer 1 (CSR gather, 16->64) ====================
// One wave per node (50k waves: machine stays full). Coalesced WeT1 prologue.
// Inner loop: chunk-broadcast (1 coalesced float4/lane per 16 edges,
// readlane -> SGPR), chained bias-seeded FMA, next-chunk prefetch.
__global__ __launch_bounds__(256, 4) void k_edge1(
    const int* __restrict__ rp, const int* __restrict__ srcs,
    const float* __restrict__ eaw,
    const float* __restrict__ WeT1, const float* __restrict__ be1,
    const float* __restrict__ x, float* __restrict__ out)
{
    const int lane = threadIdx.x & 63;
    const int node = blockIdx.x * 4 + (threadIdx.x >> 6);
    if (node >= N_NODES) return;

    float wr[16];
#pragma unroll
    for (int k = 0; k < 16; ++k) wr[k] = WeT1[k * 64 + lane];   // coalesced 256B
    const float bias = be1[lane];

    const int beg = rp[node], end = rp[node + 1];
    float acc = 0.f;

    if (beg < end) {
        int l16 = beg + (lane & 15);
        int sl = srcs[l16 < end ? l16 : end - 1];
        float4 ev = *(const float4*)(eaw + (size_t)beg * 16 + lane * 4);
        for (int c = beg; c < end; c += 16) {
            const int cp = (c + 16 < end) ? c + 16 : c;      // prefetch chunk
            const int lp = cp + (lane & 15);
            const int sln = srcs[lp < end ? lp : end - 1];
            const float4 evn = *(const float4*)(eaw + (size_t)cp * 16 + lane * 4);
            const int n = end - c < 16 ? end - c : 16;       // uniform per wave
#pragma unroll 8
            for (int j = 0; j < n; ++j) {
                const int src = __builtin_amdgcn_readlane(sl, j);
                const float hv = x[(size_t)src * 64 + lane];
                const int L = 4 * j;
                float d = bias;
                d = fmaf(__rlf(ev.x, L),     wr[0],  d);
                d = fmaf(__rlf(ev.y, L),     wr[1],  d);
                d = fmaf(__rlf(ev.z, L),     wr[2],  d);
                d = fmaf(__rlf(ev.w, L),     wr[3],  d);
                d = fmaf(__rlf(ev.x, L + 1), wr[4],  d);
                d = fmaf(__rlf(ev.y, L + 1), wr[5],  d);
                d = fmaf(__rlf(ev.z, L + 1), wr[6],  d);
                d = fmaf(__rlf(ev.w, L + 1), wr[7],  d);
                d = fmaf(__rlf(ev.x, L + 2), wr[8],  d);
                d = fmaf(__rlf(ev.y, L + 2), wr[9],  d);
                d = fmaf(__rlf(ev.z, L + 2), wr[10], d);
                d = fmaf(__rlf(ev.w, L + 2), wr[11], d);
                d = fmaf(__rlf(ev.x, L + 3), wr[12], d);
                d = fmaf(__rlf(ev.y, L + 3), wr[13], d);
                d = fmaf(__rlf(ev.z, L + 3), wr[14], d);
                d = fmaf(__rlf(ev.w, L + 3), wr[15], d);
                acc += fmaxf(hv + d, 0.f);
            }
            sl = sln; ev = evn;
        }
    }
    out[(size_t)node * 64 + lane] = x[(size_t)node * 64 + lane] + acc;
}

// ===================== Edge layer 2 (CSR gather, 16->128) ===================
// One wave per node; lane owns dims (2*lane, 2*lane+1); coalesced WeT2
// prologue (16x 512B float2 loads).
__global__ __launch_bounds__(256, 4) void k_edge2(
    const int* __restrict__ rp, const int* __restrict__ srcs,
    const float* __restrict__ eaw,
    const float* __restrict__ WeT2, const float* __restrict__ be2,
    const float* __restrict__ h, float* __restrict__ out)
{
    const int lane = threadIdx.x & 63;
    const int node = blockIdx.x * 4 + (threadIdx.x >> 6);
    if (node >= N_NODES) return;

    const int dA = 2 * lane;
    float wrA[16], wrB[16];
#pragma unroll
    for (int k = 0; k < 16; ++k) {
        const float2 w = *(const float2*)(WeT2 + k * 128 + dA);  // coalesced 512B
        wrA[k] = w.x; wrB[k] = w.y;
    }
    const float2 bv = *(const float2*)(be2 + dA);
    const float biasA = bv.x, biasB = bv.y;

    const int beg = rp[node], end = rp[node + 1];
    float accA = 0.f, accB = 0.f;

    if (beg < end) {
        int l16 = beg + (lane & 15);
        int sl = srcs[l16 < end ? l16 : end - 1];
        float4 ev = *(const float4*)(eaw + (size_t)beg * 16 + lane * 4);
        for (int c = beg; c < end; c += 16) {
            const int cp = (c + 16 < end) ? c + 16 : c;
            const int lp = cp + (lane & 15);
            const int sln = srcs[lp < end ? lp : end - 1];
            const float4 evn = *(const float4*)(eaw + (size_t)cp * 16 + lane * 4);
            const int n = end - c < 16 ? end - c : 16;
#pragma unroll 4
            for (int j = 0; j < n; ++j) {
                const int src = __builtin_amdgcn_readlane(sl, j);
                const float2 hv = *(const float2*)(h + (size_t)src * 128 + dA);
                const int L = 4 * j;
                const float e0  = __rlf(ev.x, L),     e1  = __rlf(ev.y, L);
                const float e2  = __rlf(ev.z, L),     e3  = __rlf(ev.w, L);
                const float e4  = __rlf(ev.x, L + 1), e5  = __rlf(ev.y, L + 1);
                const float e6  = __rlf(ev.z, L + 1), e7  = __rlf(ev.w, L + 1);
                const float e8  = __rlf(ev.x, L + 2), e9  = __rlf(ev.y, L + 2);
                const float e10 = __rlf(ev.z, L + 2), e11 = __rlf(ev.w, L + 2);
                const float e12 = __rlf(ev.x, L + 3), e13 = __rlf(ev.y, L + 3);
                const float e14 = __rlf(ev.z, L + 3), e15 = __rlf(ev.w, L + 3);
                float dA_ = biasA;
                dA_ = fmaf(e0,  wrA[0],  dA_); dA_ = fmaf(e1,  wrA[1],  dA_);
                dA_ = fmaf(e2,  wrA[2],  dA_); dA_ = fmaf(e3,  wrA[3],  dA_);
                dA_ = fmaf(e4,  wrA[4],  dA_); dA_ = fmaf(e5,  wrA[5],  dA_);
                dA_ = fmaf(e6,  wrA[6],  dA_); dA_ = fmaf(e7,  wrA[7],  dA_);
                dA_ = fmaf(e8,  wrA[8],  dA_); dA_ = fmaf(e9,  wrA[9],  dA_);
                dA_ = fmaf(e10, wrA[10], dA_); dA_ = fmaf(e11, wrA[11], dA_);
                dA_ = fmaf(e12, wrA[12], dA_); dA_ = fmaf(e13, wrA[13], dA_);
                dA_ = fmaf(e14, wrA[14], dA_); dA_ = fmaf(e15, wrA[15], dA_);
                float dB_ = biasB;
                dB_ = fmaf(e0,  wrB[0],  dB_); dB_ = fmaf(e1,  wrB[1],  dB_);
                dB_ = fmaf(e2,  wrB[2],  dB_); dB_ = fmaf(e3,  wrB[3],  dB_);
                dB_ = fmaf(e4,  wrB[4],  dB_); dB_ = fmaf(e5,  wrB[5],  dB_);
                dB_ = fmaf(e6,  wrB[6],  dB_); dB_ = fmaf(e7,  wrB[7],  dB_);
                dB_ = fmaf(e8,  wrB[8],  dB_); dB_ = fmaf(e9,  wrB[9],  dB_);
                dB_ = fmaf(e10, wrB[10], dB_); dB_ = fmaf(e11, wrB[11], dB_);
                dB_ = fmaf(e12, wrB[12], dB_); dB_ = fmaf(e13, wrB[13], dB_);
                dB_ = fmaf(e14, wrB[14], dB_); dB_ = fmaf(e15, wrB[15], dB_);
                accA += fmaxf(hv.x + dA_, 0.f);
                accB += fmaxf(hv.y + dB_, 0.f);
            }
            sl = sln; ev = evn;
        }
    }
    const float2 self = *(const float2*)(h + (size_t)node * 128 + dA);
    *(float2*)(out + (size_t)node * 128 + dA) =
        make_float2(self.x + accA, self.y + accB);
}

// ========================= Dense GEMM (node MLP) ============================
// OUT[n][j] = act( sum_k H[n][k]*WT[k][j] + b[j] ),  WT pre-transposed.
// Wave wv owns j = 32*wv..32*wv+31 (wave-uniform -> SGPR W row); lane owns
// nodes (lane, lane+64). LDS = transposed H tile only (66 KB -> 2 blocks/CU).
// In-place safe (H==OUT): block reads only rows [base, base+NT).
#define NT 128

template<int KIN, int JOUT, bool RELU>
__global__ __launch_bounds__(256) void k_mlp(
    const float* __restrict__ H, const float* __restrict__ WT,
    const float* __restrict__ b, float* __restrict__ OUT)
{
    extern __shared__ float hT[];          // [KIN][129]
    const int tid  = threadIdx.x;
    const int lane = tid & 63;
    const int wv   = __builtin_amdgcn_readfirstlane(tid >> 6);
    const int j0   = wv * 32;
    const int base = blockIdx.x * NT;

    for (int idx = tid; idx < NT * (KIN / 4); idx += 256) {
        const int q = idx & (KIN / 4 - 1);
        const int n = idx / (KIN / 4);
        const int ng = (base + n < N_NODES) ? (base + n) : (N_NODES - 1);
        const float4 v = *(const float4*)(H + (size_t)ng * KIN + 4 * q);
        hT[(4 * q + 0) * 129 + n] = v.x;
        hT[(4 * q + 1) * 129 + n] = v.y;
        hT[(4 * q + 2) * 129 + n] = v.z;
        hT[(4 * q + 3) * 129 + n] = v.w;
    }
    __syncthreads();

    float acc0[32], acc1[32];
#pragma unroll
    for (int m = 0; m < 32; ++m) { acc0[m] = 0.f; acc1[m] = 0.f; }

    float wc[32];
#pragma unroll
    for (int m = 0; m < 32; ++m) wc[m] = WT[j0 + m];
    float h0 = hT[lane], h1 = hT[lane + 64];

    for (int k = 0; k < KIN - 1; ++k) {
        float wn[32];
#pragma unroll
        for (int m = 0; m < 32; ++m) wn[m] = WT[(k + 1) * 128 + j0 + m];
        const float h0n = hT[(k + 1) * 129 + lane];
        const float h1n = hT[(k + 1) * 129 + lane + 64];
#pragma unroll
        for (int m = 0; m < 32; ++m) {
            acc0[m] = fmaf(h0, wc[m], acc0[m]);
            acc1[m] = fmaf(h1, wc[m], acc1[m]);
        }
#pragma unroll
        for (int m = 0; m < 32; ++m) wc[m] = wn[m];
        h0 = h0n; h1 = h1n;
    }
#pragma unroll
    for (int m = 0; m < 32; ++m) {
        acc0[m] = fmaf(h0, wc[m], acc0[m]);
        acc1[m] = fmaf(h1, wc[m], acc1[m]);
    }

    float bv[32];
#pragma unroll
    for (int m = 0; m < 32; ++m) bv[m] = (j0 + m < JOUT) ? b[j0 + m] : 0.f;

    const int n0 = base + lane, n1 = base + lane + 64;
    if (n0 < N_NODES) {
        float* row = OUT + (size_t)n0 * JOUT;
#pragma unroll
        for (int g = 0; g < 8; ++g) {
            if (j0 + 4 * g < JOUT) {
                float4 v;
                v.x = acc0[4 * g + 0] + bv[4 * g + 0];
                v.y = acc0[4 * g + 1] + bv[4 * g + 1];
                v.z = acc0[4 * g + 2] + bv[4 * g + 2];
                v.w = acc0[4 * g + 3] + bv[4 * g + 3];
                if (RELU) {
                    v.x = fmaxf(v.x, 0.f); v.y = fmaxf(v.y, 0.f);
                    v.z = fmaxf(v.z, 0.f); v.w = fmaxf(v.w, 0.f);
                }
                *(float4*)(row + j0 + 4 * g) = v;
            }
        }
    }
    if (n1 < N_NODES) {
        float* row = OUT + (size_t)n1 * JOUT;
#pragma unroll
        for (int g = 0; g < 8; ++g) {
            if (j0 + 4 * g < JOUT) {
                float4 v;
                v.x = acc1[4 * g + 0] + bv[4 * g + 0];
                v.y = acc1[4 * g + 1] + bv[4 * g + 1];
                v.z = acc1[4 * g + 2] + bv[4 * g + 2];
                v.w = acc1[4 * g + 3] + bv[4 * g + 3];
                if (RELU) {
                    v.x = fmaxf(v.x, 0.f); v.y = fmaxf(v.y, 0.f);
                    v.z = fmaxf(v.z, 0.f); v.w = fmaxf(v.w, 0.f);
                }
                *(float4*)(row + j0 + 4 * g) = v;
            }
        }
    }
}

// ============================================================================
// Workspace layout (peak 106,118,144 B), lifetimes packed:
//   [0,        204800)  rowptr            (build .. edge2)
//   [204800,  3404800)  srcs              (prep .. edge2)
//       cnt    @204800  (hist..scan, dead before srcs written)
//       cursor @409600  (scan..scatter, dead before srcs written)
//   [3404800, 54604800) eaw  51.2MB       (prep .. edge2)
//     NOTE: edge kernels may over-read up to 1KB past a row's end (chunk
//     granularity); bytes land in t1 region (allocated), values unused.
//   [54604800,80204800) t1 (=h1) 25.6MB   (mlp11 .. edge2-in)
//       pairs @54604800 6.4MB             (scatter..prep, dead before t1)
//   [80204800,105804800) h2pre 25.6MB     (edge2-out .. head, in-place MLPs)
//       h1pre @80204800 12.8MB            (edge1..mlp11, dead before h2pre)
//   [105804800,106116096) WT 311,296 B    (k_wt .. head; incl WeT1/WeT2)
//   [106116096,106118144) bsum/boff 2KB   (scan only)
extern "C" void kernel_launch(void* const* d_in, const int* in_sizes, int n_in,
                              void* d_out, int out_size, void* d_ws, size_t ws_size,
                              hipStream_t stream) {
    const float* x     = (const float*)d_in[0];
    const int*   ei    = (const int*)  d_in[1];
    const float* eattr = (const float*)d_in[2];
    const float* ew    = (const float*)d_in[3];
    const float* We1   = (const float*)d_in[4];
    const float* be1   = (const float*)d_in[5];
    const float* W11   = (const float*)d_in[6];
    const float* b11   = (const float*)d_in[7];
    const float* W12   = (const float*)d_in[8];
    const float* b12   = (const float*)d_in[9];
    const float* We2   = (const float*)d_in[10];
    const float* be2   = (const float*)d_in[11];
    const float* W21   = (const float*)d_in[12];
    const float* b21   = (const float*)d_in[13];
    const float* W22   = (const float*)d_in[14];
    const float* b22   = (const float*)d_in[15];
    const float* Wo    = (const float*)d_in[16];
    const float* bo    = (const float*)d_in[17];
    float* out = (float*)d_out;

    char* ws = (char*)d_ws;
    int*   rowptr = (int*)  (ws + 0);
    int*   cnt    = (int*)  (ws + 204800);
    int*   cursor = (int*)  (ws + 409600);
    int*   srcs   = (int*)  (ws + 204800);     // overlays cnt+cursor (dead)
    float* eaw    = (float*)(ws + 3404800);    // 51.2 MB
    float* t1     = (float*)(ws + 54604800);   // 25.6 MB (h1 alias)
    int2*  pairs  = (int2*) (ws + 54604800);   // 6.4 MB, dead before t1 written
    float* h2pre  = (float*)(ws + 80204800);   // 25.6 MB
    float* h1pre  = (float*)(ws + 80204800);   // 12.8 MB, dead before h2pre
    float* WT     = (float*)(ws + 105804800);  // 311,296 B
    float* WT11 = WT;           // [64][128]
    float* WT12 = WT + 8192;    // [128][128]
    float* WT21 = WT + 24576;
    float* WT22 = WT + 40960;
    float* WTo  = WT + 57344;   // [128][128] zero-padded j>=100
    float* WeT1 = WT + 73728;   // [16][64]
    float* WeT2 = WT + 74752;   // [16][128]
    int*   bsum = (int*)(ws + 106116096);      // 196 ints (pad 1KB)
    int*   boff = (int*)(ws + 106117120);      // 196 ints

    hipMemsetAsync(cnt, 0, 200000, stream);

    k_wt<<<300, 256, 0, stream>>>(W11, W12, W21, W22, Wo, We1, We2, WT);

    const int EB = (E_EDGES + 255) / 256;      // 3125
    k_hist<<<EB, 256, 0, stream>>>(ei, cnt);
    k_scan1<<<SCAN_NB, 256, 0, stream>>>(cnt, bsum);
    k_scan2<<<1, 256, 0, stream>>>(bsum, boff);
    k_scan3<<<SCAN_NB, 256, 0, stream>>>(cnt, boff, rowptr, cursor);
    k_scatter<<<EB, 256, 0, stream>>>(ei, cursor, pairs);

    const int PB = (E_EDGES * 4 + 255) / 256;  // 12500
    k_prep<<<PB, 256, 0, stream>>>(pairs, eattr, ew, eaw, srcs);

    const int NB = (N_NODES + 3) / 4;          // 12500 (one wave per node)
    k_edge1<<<NB, 256, 0, stream>>>(rowptr, srcs, eaw, WeT1, be1, x, h1pre);

    const int TILES = (N_NODES + NT - 1) / NT;          // 391
    const size_t lds64  = (size_t)(64  * 129) * 4;      // 33,024 B
    const size_t lds128 = (size_t)(128 * 129) * 4;      // 66,048 B

    k_mlp<64, 128, true><<<TILES, 256, lds64, stream>>>(h1pre, WT11, b11, t1);
    k_mlp<128, 128, true><<<TILES, 256, lds128, stream>>>(t1, WT12, b12, t1);

    k_edge2<<<NB, 256, 0, stream>>>(rowptr, srcs, eaw, WeT2, be2, t1, h2pre);

    k_mlp<128, 128, true><<<TILES, 256, lds128, stream>>>(h2pre, WT21, b21, h2pre);
    k_mlp<128, 128, true><<<TILES, 256, lds128, stream>>>(h2pre, WT22, b22, h2pre);
    k_mlp<128, 100, false><<<TILES, 256, lds128, stream>>>(h2pre, WTo, bo, out);
}

// Round 7
// 550.715 us; speedup vs baseline: 1.4315x; 1.1264x over previous
//
#include <hip/hip_runtime.h>

#define N_NODES 50000
#define E_EDGES 800000
#define SCAN_NB 196   // 196*256 = 50176 >= N_NODES

// ============================ CSR build =====================================
__global__ __launch_bounds__(256) void k_hist(
    const int* __restrict__ ei, int* __restrict__ cnt)
{
    const int e = blockIdx.x * 256 + threadIdx.x;
    if (e < E_EDGES) atomicAdd(&cnt[ei[E_EDGES + e]], 1);
}

// ---- two-level parallel exclusive scan -------------------------------------
__global__ __launch_bounds__(256) void k_scan1(
    const int* __restrict__ cnt, int* __restrict__ bsum)
{
    __shared__ int red[256];
    const int tid = threadIdx.x;
    const int i = blockIdx.x * 256 + tid;
    red[tid] = (i < N_NODES) ? cnt[i] : 0;
    __syncthreads();
    for (int off = 128; off > 0; off >>= 1) {
        if (tid < off) red[tid] += red[tid + off];
        __syncthreads();
    }
    if (tid == 0) bsum[blockIdx.x] = red[0];
}

__global__ __launch_bounds__(256) void k_scan2(
    const int* __restrict__ bsum, int* __restrict__ boff)
{
    __shared__ int part[256];
    const int tid = threadIdx.x;
    const int v = (tid < SCAN_NB) ? bsum[tid] : 0;
    part[tid] = v;
    __syncthreads();
    for (int off = 1; off < 256; off <<= 1) {
        const int vv = part[tid];
        const int u = (tid >= off) ? part[tid - off] : 0;
        __syncthreads();
        part[tid] = vv + u;
        __syncthreads();
    }
    if (tid < SCAN_NB) boff[tid] = part[tid] - v;   // exclusive block offset
}

__global__ __launch_bounds__(256) void k_scan3(
    const int* __restrict__ cnt, const int* __restrict__ boff,
    int* __restrict__ rowptr, int* __restrict__ cursor)
{
    __shared__ int part[256];
    const int tid = threadIdx.x;
    const int i = blockIdx.x * 256 + tid;
    const int v = (i < N_NODES) ? cnt[i] : 0;
    part[tid] = v;
    __syncthreads();
    for (int off = 1; off < 256; off <<= 1) {
        const int vv = part[tid];
        const int u = (tid >= off) ? part[tid - off] : 0;
        __syncthreads();
        part[tid] = vv + u;
        __syncthreads();
    }
    const int excl = part[tid] - v + boff[blockIdx.x];
    if (i < N_NODES) { rowptr[i] = excl; cursor[i] = excl; }
    if (i == N_NODES) rowptr[N_NODES] = excl;  // beyond-end v=0 => excl = total
}

__global__ __launch_bounds__(256) void k_scatter(
    const int* __restrict__ ei, int* __restrict__ cursor, int2* __restrict__ pairs)
{
    const int e = blockIdx.x * 256 + threadIdx.x;
    if (e < E_EDGES) {
        const int dst = ei[E_EDGES + e];
        const int pos = atomicAdd(&cursor[dst], 1);
        pairs[pos] = make_int2(ei[e], e);
    }
}

// ============ CSR-order edge-attr pre-scale (kills gather deps) =============
__global__ __launch_bounds__(256) void k_prep(
    const int2* __restrict__ pairs, const float* __restrict__ eattr,
    const float* __restrict__ ew, float* __restrict__ eaw, int* __restrict__ srcs)
{
    const int t = blockIdx.x * 256 + threadIdx.x;
    const int pos = t >> 2;
    if (pos >= E_EDGES) return;
    const int q = t & 3;
    const int2 p = pairs[pos];
    if (q == 0) srcs[pos] = p.x;
    const float w = ew[p.y];
    const float4 a = *((const float4*)(eattr + (size_t)p.y * 16) + q);
    *((float4*)(eaw + (size_t)pos * 16) + q) =
        make_float4(a.x * w, a.y * w, a.z * w, a.w * w);
}

// ================== Weight transposes (once, tiny) ==========================
// WT segments (float offsets): WT11@0 [64][128], WT12@8192 [128][128],
// WT21@24576, WT22@40960, WTo@57344 [128][128] (j>=100 zero-padded),
// WeT1@73728 [16][64], WeT2@74752 [16][128].
__global__ __launch_bounds__(256) void k_wt(
    const float* __restrict__ W11, const float* __restrict__ W12,
    const float* __restrict__ W21, const float* __restrict__ W22,
    const float* __restrict__ Wo,
    const float* __restrict__ We1, const float* __restrict__ We2,
    float* __restrict__ WT)
{
    const int bid = blockIdx.x;
    const int tid = threadIdx.x;
    if (bid < 288) {
        const float* src; int KIN, JOUT, lbase, obase;
        if (bid < 32)       { src = W11; KIN = 64;  JOUT = 128; lbase = 0;   obase = 0; }
        else if (bid < 96)  { src = W12; KIN = 128; JOUT = 128; lbase = 32;  obase = 8192; }
        else if (bid < 160) { src = W21; KIN = 128; JOUT = 128; lbase = 96;  obase = 24576; }
        else if (bid < 224) { src = W22; KIN = 128; JOUT = 128; lbase = 160; obase = 40960; }
        else                { src = Wo;  KIN = 128; JOUT = 100; lbase = 224; obase = 57344; }
        const int idx = (bid - lbase) * 256 + tid;   // < KIN*128
        const int k = idx >> 7, j = idx & 127;
        WT[obase + idx] = (j < JOUT) ? src[j * KIN + k] : 0.f;
    } else if (bid < 292) {                   // WeT1[k][d] = We1[d][k]
        const int idx = (bid - 288) * 256 + tid;     // < 1024
        const int k = idx >> 6, d = idx & 63;
        WT[73728 + idx] = We1[d * 16 + k];
    } else {                                  // WeT2[k][d] = We2[d][k]
        const int idx = (bid - 292) * 256 + tid;     // < 2048
        const int k = idx >> 7, d = idx & 127;
        WT[74752 + idx] = We2[d * 16 + k];
    }
}

// ===================== Edge layer 1 (CSR gather, 16->64) ====================
// One wave per node; node forced wave-uniform (readfirstlane, k_mlp idiom) so
// rp / srcs / eaw reads have UNIFORM addresses -> compiler emits s_load
// through the scalar pipe into SGPRs (zero VALU, zero VMEM; fmaf takes one
// SGPR operand). Inner loop: 16 FMA + coalesced x-row read per edge.
__global__ __launch_bounds__(256, 4) void k_edge1(
    const int* __restrict__ rp, const int* __restrict__ srcs,
    const float* __restrict__ eaw,
    const float* __restrict__ WeT1, const float* __restrict__ be1,
    const float* __restrict__ x, float* __restrict__ out)
{
    const int lane = threadIdx.x & 63;
    const int node =
        __builtin_amdgcn_readfirstlane(blockIdx.x * 4 + (threadIdx.x >> 6));
    if (node >= N_NODES) return;

    float wr[16];
#pragma unroll
    for (int k = 0; k < 16; ++k) wr[k] = WeT1[k * 64 + lane];   // coalesced 256B
    const float bias = be1[lane];

    const int beg = rp[node], end = rp[node + 1];               // s_load
    float acc = 0.f;

#pragma unroll 4
    for (int c = beg; c < end; ++c) {
        const int src = srcs[c];                     // uniform -> s_load
        const float hv = x[(size_t)src * 64 + lane]; // coalesced row read
        const float* ep = eaw + (size_t)c * 16;      // uniform -> s_load x16
        float d = bias;
#pragma unroll
        for (int k = 0; k < 16; ++k) d = fmaf(ep[k], wr[k], d);
        acc += fmaxf(hv + d, 0.f);
    }
    out[(size_t)node * 64 + lane] = x[(size_t)node * 64 + lane] + acc;
}

// ===================== Edge layer 2 (CSR gather, 16->128) ===================
// Lane owns dims (2*lane, 2*lane+1); same scalar-pipe scheme; the 16 SGPR
// edge values feed BOTH dot chains.
__global__ __launch_bounds__(256, 4) void k_edge2(
    const int* __restrict__ rp, const int* __restrict__ srcs,
    const float* __restrict__ eaw,
    const float* __restrict__ WeT2, const float* __restrict__ be2,
    const float* __restrict__ h, float* __restrict__ out)
{
    const int lane = threadIdx.x & 63;
    const int node =
        __builtin_amdgcn_readfirstlane(blockIdx.x * 4 + (threadIdx.x >> 6));
    if (node >= N_NODES) return;

    const int dA = 2 * lane;
    float wrA[16], wrB[16];
#pragma unroll
    for (int k = 0; k < 16; ++k) {
        const float2 w = *(const float2*)(WeT2 + k * 128 + dA);  // coalesced 512B
        wrA[k] = w.x; wrB[k] = w.y;
    }
    const float2 bv = *(const float2*)(be2 + dA);
    const float biasA = bv.x, biasB = bv.y;

    const int beg = rp[node], end = rp[node + 1];                // s_load
    float accA = 0.f, accB = 0.f;

    const float* hrow = h + dA;

#pragma unroll 4
    for (int c = beg; c < end; ++c) {
        const int src = srcs[c];                      // uniform -> s_load
        const float2 hv = *(const float2*)(hrow + (size_t)src * 128);
        const float* ep = eaw + (size_t)c * 16;       // uniform -> s_load x16
        float dA_ = biasA, dB_ = biasB;
#pragma unroll
        for (int k = 0; k < 16; ++k) {
            dA_ = fmaf(ep[k], wrA[k], dA_);
            dB_ = fmaf(ep[k], wrB[k], dB_);
        }
        accA += fmaxf(hv.x + dA_, 0.f);
        accB += fmaxf(hv.y + dB_, 0.f);
    }
    const float2 self = *(const float2*)(h + (size_t)node * 128 + dA);
    *(float2*)(out + (size_t)node * 128 + dA) =
        make_float2(self.x + accA, self.y + accB);
}

// ========================= Dense GEMM (node MLP) ============================
// OUT[n][j] = act( sum_k H[n][k]*WT[k][j] + b[j] ),  WT pre-transposed.
// Wave wv owns j = 32*wv..32*wv+31 (wave-uniform -> SGPR W row); lane owns
// nodes (lane, lane+64). LDS = transposed H tile only (66 KB -> 2 blocks/CU).
// In-place safe (H==OUT): block reads only rows [base, base+NT).
#define NT 128

template<int KIN, int JOUT, bool RELU>
__global__ __launch_bounds__(256) void k_mlp(
    const float* __restrict__ H, const float* __restrict__ WT,
    const float* __restrict__ b, float* __restrict__ OUT)
{
    extern __shared__ float hT[];          // [KIN][129]
    const int tid  = threadIdx.x;
    const int lane = tid & 63;
    const int wv   = __builtin_amdgcn_readfirstlane(tid >> 6);
    const int j0   = wv * 32;
    const int base = blockIdx.x * NT;

    for (int idx = tid; idx < NT * (KIN / 4); idx += 256) {
        const int q = idx & (KIN / 4 - 1);
        const int n = idx / (KIN / 4);
        const int ng = (base + n < N_NODES) ? (base + n) : (N_NODES - 1);
        const float4 v = *(const float4*)(H + (size_t)ng * KIN + 4 * q);
        hT[(4 * q + 0) * 129 + n] = v.x;
        hT[(4 * q + 1) * 129 + n] = v.y;
        hT[(4 * q + 2) * 129 + n] = v.z;
        hT[(4 * q + 3) * 129 + n] = v.w;
    }
    __syncthreads();

    float acc0[32], acc1[32];
#pragma unroll
    for (int m = 0; m < 32; ++m) { acc0[m] = 0.f; acc1[m] = 0.f; }

    float wc[32];
#pragma unroll
    for (int m = 0; m < 32; ++m) wc[m] = WT[j0 + m];
    float h0 = hT[lane], h1 = hT[lane + 64];

    for (int k = 0; k < KIN - 1; ++k) {
        float wn[32];
#pragma unroll
        for (int m = 0; m < 32; ++m) wn[m] = WT[(k + 1) * 128 + j0 + m];
        const float h0n = hT[(k + 1) * 129 + lane];
        const float h1n = hT[(k + 1) * 129 + lane + 64];
#pragma unroll
        for (int m = 0; m < 32; ++m) {
            acc0[m] = fmaf(h0, wc[m], acc0[m]);
            acc1[m] = fmaf(h1, wc[m], acc1[m]);
        }
#pragma unroll
        for (int m = 0; m < 32; ++m) wc[m] = wn[m];
        h0 = h0n; h1 = h1n;
    }
#pragma unroll
    for (int m = 0; m < 32; ++m) {
        acc0[m] = fmaf(h0, wc[m], acc0[m]);
        acc1[m] = fmaf(h1, wc[m], acc1[m]);
    }

    float bv[32];
#pragma unroll
    for (int m = 0; m < 32; ++m) bv[m] = (j0 + m < JOUT) ? b[j0 + m] : 0.f;

    const int n0 = base + lane, n1 = base + lane + 64;
    if (n0 < N_NODES) {
        float* row = OUT + (size_t)n0 * JOUT;
#pragma unroll
        for (int g = 0; g < 8; ++g) {
            if (j0 + 4 * g < JOUT) {
                float4 v;
                v.x = acc0[4 * g + 0] + bv[4 * g + 0];
                v.y = acc0[4 * g + 1] + bv[4 * g + 1];
                v.z = acc0[4 * g + 2] + bv[4 * g + 2];
                v.w = acc0[4 * g + 3] + bv[4 * g + 3];
                if (RELU) {
                    v.x = fmaxf(v.x, 0.f); v.y = fmaxf(v.y, 0.f);
                    v.z = fmaxf(v.z, 0.f); v.w = fmaxf(v.w, 0.f);
                }
                *(float4*)(row + j0 + 4 * g) = v;
            }
        }
    }
    if (n1 < N_NODES) {
        float* row = OUT + (size_t)n1 * JOUT;
#pragma unroll
        for (int g = 0; g < 8; ++g) {
            if (j0 + 4 * g < JOUT) {
                float4 v;
                v.x = acc1[4 * g + 0] + bv[4 * g + 0];
                v.y = acc1[4 * g + 1] + bv[4 * g + 1];
                v.z = acc1[4 * g + 2] + bv[4 * g + 2];
                v.w = acc1[4 * g + 3] + bv[4 * g + 3];
                if (RELU) {
                    v.x = fmaxf(v.x, 0.f); v.y = fmaxf(v.y, 0.f);
                    v.z = fmaxf(v.z, 0.f); v.w = fmaxf(v.w, 0.f);
                }
                *(float4*)(row + j0 + 4 * g) = v;
            }
        }
    }
}

// ============================================================================
// Workspace layout (peak 106,118,144 B), lifetimes packed:
//   [0,        204800)  rowptr            (build .. edge2)
//   [204800,  3404800)  srcs              (prep .. edge2)
//       cnt    @204800  (hist..scan, dead before srcs written)
//       cursor @409600  (scan..scatter, dead before srcs written)
//   [3404800, 54604800) eaw  51.2MB       (prep .. edge2)
//   [54604800,80204800) t1 (=h1) 25.6MB   (mlp11 .. edge2-in)
//       pairs @54604800 6.4MB             (scatter..prep, dead before t1)
//   [80204800,105804800) h2pre 25.6MB     (edge2-out .. head, in-place MLPs)
//       h1pre @80204800 12.8MB            (edge1..mlp11, dead before h2pre)
//   [105804800,106116096) WT 311,296 B    (k_wt .. head; incl WeT1/WeT2)
//   [106116096,106118144) bsum/boff 2KB   (scan only)
extern "C" void kernel_launch(void* const* d_in, const int* in_sizes, int n_in,
                              void* d_out, int out_size, void* d_ws, size_t ws_size,
                              hipStream_t stream) {
    const float* x     = (const float*)d_in[0];
    const int*   ei    = (const int*)  d_in[1];
    const float* eattr = (const float*)d_in[2];
    const float* ew    = (const float*)d_in[3];
    const float* We1   = (const float*)d_in[4];
    const float* be1   = (const float*)d_in[5];
    const float* W11   = (const float*)d_in[6];
    const float* b11   = (const float*)d_in[7];
    const float* W12   = (const float*)d_in[8];
    const float* b12   = (const float*)d_in[9];
    const float* We2   = (const float*)d_in[10];
    const float* be2   = (const float*)d_in[11];
    const float* W21   = (const float*)d_in[12];
    const float* b21   = (const float*)d_in[13];
    const float* W22   = (const float*)d_in[14];
    const float* b22   = (const float*)d_in[15];
    const float* Wo    = (const float*)d_in[16];
    const float* bo    = (const float*)d_in[17];
    float* out = (float*)d_out;

    char* ws = (char*)d_ws;
    int*   rowptr = (int*)  (ws + 0);
    int*   cnt    = (int*)  (ws + 204800);
    int*   cursor = (int*)  (ws + 409600);
    int*   srcs   = (int*)  (ws + 204800);     // overlays cnt+cursor (dead)
    float* eaw    = (float*)(ws + 3404800);    // 51.2 MB
    float* t1     = (float*)(ws + 54604800);   // 25.6 MB (h1 alias)
    int2*  pairs  = (int2*) (ws + 54604800);   // 6.4 MB, dead before t1 written
    float* h2pre  = (float*)(ws + 80204800);   // 25.6 MB
    float* h1pre  = (float*)(ws + 80204800);   // 12.8 MB, dead before h2pre
    float* WT     = (float*)(ws + 105804800);  // 311,296 B
    float* WT11 = WT;           // [64][128]
    float* WT12 = WT + 8192;    // [128][128]
    float* WT21 = WT + 24576;
    float* WT22 = WT + 40960;
    float* WTo  = WT + 57344;   // [128][128] zero-padded j>=100
    float* WeT1 = WT + 73728;   // [16][64]
    float* WeT2 = WT + 74752;   // [16][128]
    int*   bsum = (int*)(ws + 106116096);      // 196 ints (pad 1KB)
    int*   boff = (int*)(ws + 106117120);      // 196 ints

    hipMemsetAsync(cnt, 0, 200000, stream);

    k_wt<<<300, 256, 0, stream>>>(W11, W12, W21, W22, Wo, We1, We2, WT);

    const int EB = (E_EDGES + 255) / 256;      // 3125
    k_hist<<<EB, 256, 0, stream>>>(ei, cnt);
    k_scan1<<<SCAN_NB, 256, 0, stream>>>(cnt, bsum);
    k_scan2<<<1, 256, 0, stream>>>(bsum, boff);
    k_scan3<<<SCAN_NB, 256, 0, stream>>>(cnt, boff, rowptr, cursor);
    k_scatter<<<EB, 256, 0, stream>>>(ei, cursor, pairs);

    const int PB = (E_EDGES * 4 + 255) / 256;  // 12500
    k_prep<<<PB, 256, 0, stream>>>(pairs, eattr, ew, eaw, srcs);

    const int NB = (N_NODES + 3) / 4;          // 12500 (one wave per node)
    k_edge1<<<NB, 256, 0, stream>>>(rowptr, srcs, eaw, WeT1, be1, x, h1pre);

    const int TILES = (N_NODES + NT - 1) / NT;          // 391
    const size_t lds64  = (size_t)(64  * 129) * 4;      // 33,024 B
    const size_t lds128 = (size_t)(128 * 129) * 4;      // 66,048 B

    k_mlp<64, 128, true><<<TILES, 256, lds64, stream>>>(h1pre, WT11, b11, t1);
    k_mlp<128, 128, true><<<TILES, 256, lds128, stream>>>(t1, WT12, b12, t1);

    k_edge2<<<NB, 256, 0, stream>>>(rowptr, srcs, eaw, WeT2, be2, t1, h2pre);

    k_mlp<128, 128, true><<<TILES, 256, lds128, stream>>>(h2pre, WT21, b21, h2pre);
    k_mlp<128, 128, true><<<TILES, 256, lds128, stream>>>(h2pre, WT22, b22, h2pre);
    k_mlp<128, 100, false><<<TILES, 256, lds128, stream>>>(h2pre, WTo, bo, out);
}